// Round 2
// baseline (380.851 us; speedup 1.0000x reference)
//
#include <hip/hip_runtime.h>
#include <hip/hip_bf16.h>

// GAT_51788715655952: 2x MPGATConv(edge_node_concate)+Linear+LReLU+BN, pool, head.
// Strategy: counting-sort edges by dst once; per-node wave computes online-softmax
// weighted sum of ys[src] with zero atomics; edge-linear algebraically decomposed:
//   msg_e @ elw = yd[dst] + alpha_e * ys[src] + ew_e * elw[64] + elb
// so per-edge cost is ~1 exp + 32-wide FMA over a coalesced 128B gather.

#define HID 32

__global__ void k_hist(const int* __restrict__ dst, int* __restrict__ counts, int E) {
    int e = blockIdx.x * blockDim.x + threadIdx.x;
    if (e < E) atomicAdd(&counts[dst[e]], 1);
}

__global__ void k_scan(const int* __restrict__ counts, int* __restrict__ offsets,
                       int* __restrict__ cursor, int n) {
    __shared__ int partial[256];
    int chunk = (n + 255) / 256;
    int t = threadIdx.x;
    int lo = t * chunk, hi = min(lo + chunk, n);
    int s = 0;
    for (int i = lo; i < hi; i++) s += counts[i];
    partial[t] = s;
    __syncthreads();
    if (t == 0) {
        int run = 0;
        for (int i = 0; i < 256; i++) { int v = partial[i]; partial[i] = run; run += v; }
    }
    __syncthreads();
    int run = partial[t];
    for (int i = lo; i < hi; i++) {
        offsets[i] = run; cursor[i] = run;
        run += counts[i];
    }
    if (lo < n && hi == n) offsets[n] = run;
}

__global__ void k_scatter(const int* __restrict__ src, const int* __restrict__ dst,
                          const float* __restrict__ ea, int* __restrict__ cursor,
                          int* __restrict__ ssrc, float* __restrict__ sew, int E) {
    int e = blockIdx.x * blockDim.x + threadIdx.x;
    if (e >= E) return;
    int d = dst[e];
    int p = atomicAdd(&cursor[d], 1);
    ssrc[p] = src[e];
    sew[p] = fabsf(ea[e]);
}

// out[r][c] = sum_k in[r][k] * W[k][c], W is [K][32] row-major. 8 rows per 256-block.
__global__ void k_gemm32(const float* __restrict__ in, const float* __restrict__ W,
                         float* __restrict__ out, int n, int K) {
    int c = threadIdx.x & 31;
    int r = blockIdx.x * (blockDim.x >> 5) + (threadIdx.x >> 5);
    if (r >= n) return;
    const float* row = in + (size_t)r * K;
    float acc = 0.f;
    for (int k = 0; k < K; k++) acc = fmaf(row[k], W[k * HID + c], acc);
    out[r * HID + c] = acc;
}

// per-node attention logit coefficients
__global__ void k_al(const float* __restrict__ xp, const float* __restrict__ asrc,
                     const float* __restrict__ adst, float* __restrict__ als,
                     float* __restrict__ ald, int n) {
    int i = blockIdx.x * blockDim.x + threadIdx.x;
    if (i >= n) return;
    const float* xr = xp + i * HID;
    float s = 0.f, d = 0.f;
    for (int k = 0; k < HID; k++) {
        float v = xr[k];
        s = fmaf(v, asrc[k], s);
        d = fmaf(v, adst[k], d);
    }
    als[i] = s; ald[i] = d;
}

// ys = xp @ elw[32:64], yd = xp @ elw[0:32]. 4 nodes x 2 mats x 32 cols per 256-block.
__global__ void k_prep(const float* __restrict__ xp, const float* __restrict__ elw,
                       float* __restrict__ ys, float* __restrict__ yd, int n) {
    int c = threadIdx.x & 31;
    int which = (threadIdx.x >> 5) & 1;             // 0 -> yd (rows 0..31), 1 -> ys (rows 32..63)
    int node = blockIdx.x * 4 + (threadIdx.x >> 6);
    if (node >= n) return;
    const float* xr = xp + node * HID;
    const float* W = elw + which * HID * HID;
    float acc = 0.f;
    for (int k = 0; k < HID; k++) acc = fmaf(xr[k], W[k * HID + c], acc);
    (which ? ys : yd)[node * HID + c] = acc;
}

// One wave (64 lanes) per node: online-softmax weighted accumulate + fused proj+BN.
__global__ void k_gat(const int* __restrict__ offsets, const int* __restrict__ ssrc,
                      const float* __restrict__ sew, const float* __restrict__ als,
                      const float* __restrict__ ald, const float* __restrict__ ys,
                      const float* __restrict__ yd, const float* __restrict__ elw,
                      const float* __restrict__ elb, const float* __restrict__ bvec,
                      const float* __restrict__ pw, const float* __restrict__ pb,
                      const float* __restrict__ bng, const float* __restrict__ bnb,
                      float* __restrict__ zout, int n) {
    int lane = threadIdx.x & 63;
    int node = blockIdx.x * (blockDim.x >> 6) + (threadIdx.x >> 6);
    if (node >= n) return;
    int beg = offsets[node], end = offsets[node + 1];
    int deg = end - beg;
    int half = lane >> 5, l = lane & 31;
    float aldi = ald[node];
    float agg;
    if (deg > 0) {
        // online softmax: running max m per half-wave (uniform across the 32 lanes)
        float m = -INFINITY, acc = 0.f, esum = 0.f, wsum = 0.f;
        for (int e = beg + half; e < end; e += 2) {
            int j = ssrc[e];                       // uniform within half-wave
            float a = als[j] + aldi;
            a = (a >= 0.f) ? a : 0.2f * a;         // leaky relu 0.2
            if (a > m) {                           // rescale (rare, ~log(deg) times)
                float sc = __expf(m - a);          // exp(-inf)=0 on first edge
                acc *= sc; esum *= sc; m = a;
            }
            float w = __expf(a - m);
            acc = fmaf(w, ys[j * HID + l], acc);   // coalesced 128B gather
            esum += w;
            wsum += sew[e];
        }
        // merge the two half-waves (half1 may be empty when deg==1: m=-inf -> weight 0)
        float mo = __shfl_xor(m, 32);
        float M  = fmaxf(m, mo);
        float s0 = __expf(m - M);
        float s1 = __expf(mo - M);
        float se = esum * s0 + __shfl_xor(esum, 32) * s1;
        acc      = acc  * s0 + __shfl_xor(acc, 32)  * s1;
        wsum    += __shfl_xor(wsum, 32);
        agg = acc / se + wsum * elw[64 * HID + l];
    } else {
        agg = 0.f;
    }
    agg += (float)deg * (yd[node * HID + l] + elb[l]) + bvec[l];
    // projection 32x32 via shfl broadcast, then LeakyReLU + BatchNorm(eval)
    float z = 0.f;
    for (int k = 0; k < HID; k++) {
        float av = __shfl(agg, k);                 // agg[k] lives on lane k (k<32)
        z = fmaf(av, pw[k * HID + l], z);
    }
    z += pb[l];
    z = (z >= 0.f) ? z : 0.2f * z;
    const float inv = 0.99999500003749971875f;     // 1/sqrt(1+1e-5)
    z = fmaf(z, bng[l] * inv, bnb[l]);
    if (lane < 32) zout[node * HID + l] = z;
}

__global__ void k_pool(const float* __restrict__ z, const int* __restrict__ batch,
                       float* __restrict__ pool, float* __restrict__ cnt, int n) {
    int i = blockIdx.x * blockDim.x + threadIdx.x;
    int node = i >> 5, f = i & 31;
    if (node >= n) return;
    int g = batch[node];
    atomicAdd(&pool[g * HID + f], z[node * HID + f]);
    if (f == 0) atomicAdd(&cnt[g], 1.0f);
}

__global__ void k_head(const float* __restrict__ pool, const float* __restrict__ cnt,
                       const float* __restrict__ fw, const float* __restrict__ fb,
                       float* __restrict__ out, int ngraphs, int ncls) {
    int i = blockIdx.x * blockDim.x + threadIdx.x;
    if (i >= ngraphs * ncls) return;
    int g = i / ncls, c = i % ncls;
    float cc = fmaxf(cnt[g], 1.0f);
    float acc = 0.f;
    for (int k = 0; k < HID; k++) acc = fmaf(pool[g * HID + k] / cc, fw[k * ncls + c], acc);
    out[i] = acc + fb[c];
}

extern "C" void kernel_launch(void* const* d_in, const int* in_sizes, int n_in,
                              void* d_out, int out_size, void* d_ws, size_t ws_size,
                              hipStream_t stream) {
    const float* x     = (const float*)d_in[0];
    const float* ea    = (const float*)d_in[1];
    const int*   eidx  = (const int*)d_in[2];
    const int*   batch = (const int*)d_in[3];
    const float* w1    = (const float*)d_in[4];
    const float* asrc1 = (const float*)d_in[5];
    const float* adst1 = (const float*)d_in[6];
    const float* b1    = (const float*)d_in[7];
    const float* elw1  = (const float*)d_in[8];
    const float* elb1  = (const float*)d_in[9];
    const float* pw1   = (const float*)d_in[10];
    const float* pb1   = (const float*)d_in[11];
    const float* bng1  = (const float*)d_in[12];
    const float* bnb1  = (const float*)d_in[13];
    const float* w2    = (const float*)d_in[14];
    const float* asrc2 = (const float*)d_in[15];
    const float* adst2 = (const float*)d_in[16];
    const float* b2    = (const float*)d_in[17];
    const float* elw2  = (const float*)d_in[18];
    const float* elb2  = (const float*)d_in[19];
    const float* pw2   = (const float*)d_in[20];
    const float* pb2   = (const float*)d_in[21];
    const float* bng2  = (const float*)d_in[22];
    const float* bnb2  = (const float*)d_in[23];
    const float* fw    = (const float*)d_in[24];
    const float* fb    = (const float*)d_in[25];

    const int E  = in_sizes[1];
    const int N  = in_sizes[3];
    const int K1 = in_sizes[4] / HID;        // 200
    const int NCLS = in_sizes[25];           // 2
    const int NG = out_size / NCLS;          // 32

    // workspace bump allocator (floats)
    float* ws = (float*)d_ws;
    size_t off = 0;
    auto alloc = [&](size_t nelem) { size_t r = off; off += nelem; return r; };
    int*   counts  = (int*)(ws + alloc(N));
    int*   offsets = (int*)(ws + alloc(N + 1));
    int*   cursor  = (int*)(ws + alloc(N));
    int*   ssrc    = (int*)(ws + alloc(E));
    float* sew     = ws + alloc(E);
    float* xp      = ws + alloc((size_t)N * HID);
    float* ys      = ws + alloc((size_t)N * HID);
    float* yd      = ws + alloc((size_t)N * HID);
    float* zb      = ws + alloc((size_t)N * HID);
    float* als     = ws + alloc(N);
    float* ald     = ws + alloc(N);
    float* pool    = ws + alloc((size_t)NG * HID);
    float* cnt     = ws + alloc(NG);
    (void)ws_size; (void)n_in;

    hipMemsetAsync(counts, 0, N * sizeof(int), stream);
    hipMemsetAsync(pool, 0, (NG * HID + NG) * sizeof(float), stream); // pool + cnt contiguous

    // ---- sort edges by dst (shared by both blocks) ----
    k_hist<<<(E + 255) / 256, 256, 0, stream>>>(eidx + E, counts, E);
    k_scan<<<1, 256, 0, stream>>>(counts, offsets, cursor, N);
    k_scatter<<<(E + 255) / 256, 256, 0, stream>>>(eidx, eidx + E, ea, cursor, ssrc, sew, E);

    int gb = (N + 7) / 8;
    int nb4 = (N + 3) / 4;

    // ---- block 1 ----
    k_gemm32<<<gb, 256, 0, stream>>>(x, w1, xp, N, K1);
    k_al<<<(N + 255) / 256, 256, 0, stream>>>(xp, asrc1, adst1, als, ald, N);
    k_prep<<<nb4, 256, 0, stream>>>(xp, elw1, ys, yd, N);
    k_gat<<<nb4, 256, 0, stream>>>(offsets, ssrc, sew, als, ald, ys, yd,
                                   elw1, elb1, b1, pw1, pb1, bng1, bnb1, zb, N);

    // ---- block 2 ----
    k_gemm32<<<gb, 256, 0, stream>>>(zb, w2, xp, N, HID);
    k_al<<<(N + 255) / 256, 256, 0, stream>>>(xp, asrc2, adst2, als, ald, N);
    k_prep<<<nb4, 256, 0, stream>>>(xp, elw2, ys, yd, N);
    k_gat<<<nb4, 256, 0, stream>>>(offsets, ssrc, sew, als, ald, ys, yd,
                                   elw2, elb2, b2, pw2, pb2, bng2, bnb2, zb, N);

    // ---- pool + head ----
    k_pool<<<((size_t)N * HID + 255) / 256, 256, 0, stream>>>(zb, batch, pool, cnt, N);
    k_head<<<1, 64, 0, stream>>>(pool, cnt, fw, fb, (float*)d_out, NG, NCLS);
}

// Round 3
// 296.768 us; speedup vs baseline: 1.2833x; 1.2833x over previous
//
#include <hip/hip_runtime.h>
#include <hip/hip_bf16.h>

// GAT_51788715655952. Counting-sort edges by dst (2B src payload); per-node wave
// does online-softmax weighted sum of ys[src]; edge-linear decomposed:
//   agg[i] = deg*(yd[i]+elb) + (sum_e w_e*ys[src_e])/sum_e w_e + wsum[i]*elw[64] + b
// wsum via atomics in hist pass. Prep kernels fuse GEMM + attention coeffs + ys/yd.

#define HID 32

typedef unsigned short ushort_t;

__global__ void k_hist(const int* __restrict__ dst, const float* __restrict__ ea,
                       int* __restrict__ counts, float* __restrict__ wsum, int E) {
    int e = blockIdx.x * blockDim.x + threadIdx.x;
    if (e >= E) return;
    int d = dst[e];
    atomicAdd(&counts[d], 1);
    atomicAdd(&wsum[d], fabsf(ea[e]));
}

// hierarchical exclusive scan of counts[n] -> offsets[n+1], cursor[n]. 1024 threads.
__global__ void k_scan(const int* __restrict__ counts, int* __restrict__ offsets,
                       int* __restrict__ cursor, int n) {
    __shared__ int wtot[16];
    int t = threadIdx.x;
    int chunk = (n + 1023) / 1024;
    int lo = t * chunk, hi = min(lo + chunk, n);
    int s = 0;
    for (int i = lo; i < hi; i++) s += counts[i];
    int lane = t & 63, wid = t >> 6;
    int v = s;
    for (int d = 1; d < 64; d <<= 1) { int u = __shfl_up(v, d); if (lane >= d) v += u; }
    if (lane == 63) wtot[wid] = v;
    __syncthreads();
    if (wid == 0) {
        int w = (lane < 16) ? wtot[lane] : 0;
        for (int d = 1; d < 16; d <<= 1) { int u = __shfl_up(w, d); if (lane >= d) w += u; }
        if (lane < 16) wtot[lane] = w;
    }
    __syncthreads();
    int run = (wid > 0 ? wtot[wid - 1] : 0) + (v - s);   // exclusive prefix for this thread
    for (int i = lo; i < hi; i++) {
        offsets[i] = run; cursor[i] = run;
        run += counts[i];
    }
    if (lo < n && hi == n) offsets[n] = run;
}

__global__ void k_scatter(const int* __restrict__ src, const int* __restrict__ dst,
                          int* __restrict__ cursor, ushort_t* __restrict__ ssrc, int E) {
    int e = blockIdx.x * blockDim.x + threadIdx.x;
    if (e >= E) return;
    int d = dst[e];
    int p = atomicAdd(&cursor[d], 1);
    ssrc[p] = (ushort_t)src[e];
}

// shared epilogue: given xp (lane l of a 32-lane group holds xp[row][l]), compute
// als/ald (group reduce) and ys/yd (group broadcast matmul vs elw).
__device__ __forceinline__ void node_epilogue(float xp, int r, int l,
        const float* __restrict__ asrc, const float* __restrict__ adst,
        const float* __restrict__ elw,
        float* __restrict__ ys, float* __restrict__ yd,
        float* __restrict__ als, float* __restrict__ ald) {
    float ps = xp * asrc[l], pd = xp * adst[l];
    #pragma unroll
    for (int mask = 16; mask >= 1; mask >>= 1) {
        ps += __shfl_xor(ps, mask);
        pd += __shfl_xor(pd, mask);
    }
    if (l == 0) { als[r] = ps; ald[r] = pd; }
    int gbase = threadIdx.x & 32;   // group base lane within the 64-wide wave
    float yss = 0.f, ydd = 0.f;
    #pragma unroll
    for (int k = 0; k < HID; k++) {
        float xk = __shfl(xp, gbase + k);
        yss = fmaf(xk, elw[(HID + k) * HID + l], yss);
        ydd = fmaf(xk, elw[k * HID + l], ydd);
    }
    ys[r * HID + l] = yss;
    yd[r * HID + l] = ydd;
}

// block 1 prep: xp = x @ w1 (K=200, w1 staged in LDS), fused epilogue.
__global__ void k_b1prep(const float* __restrict__ x, const float* __restrict__ w1,
                         const float* __restrict__ asrc, const float* __restrict__ adst,
                         const float* __restrict__ elw,
                         float* __restrict__ ys, float* __restrict__ yd,
                         float* __restrict__ als, float* __restrict__ ald,
                         int n, int K) {
    extern __shared__ float wlds[];                 // K*32 floats
    for (int i = threadIdx.x; i < K * HID; i += blockDim.x) wlds[i] = w1[i];
    __syncthreads();
    int l = threadIdx.x & 31;
    int r = blockIdx.x * (blockDim.x >> 5) + (threadIdx.x >> 5);
    if (r >= n) return;
    const float4* rowv = (const float4*)(x + (size_t)r * K);
    float acc = 0.f;
    for (int k4 = 0; k4 < (K >> 2); k4++) {
        float4 v = rowv[k4];                        // broadcast within group
        int k = k4 << 2;
        acc = fmaf(v.x, wlds[(k + 0) * HID + l], acc);
        acc = fmaf(v.y, wlds[(k + 1) * HID + l], acc);
        acc = fmaf(v.z, wlds[(k + 2) * HID + l], acc);
        acc = fmaf(v.w, wlds[(k + 3) * HID + l], acc);
    }
    node_epilogue(acc, r, l, asrc, adst, elw, ys, yd, als, ald);
}

// block 2 prep: xp = zb @ w2 (32x32 via shfl broadcast), fused epilogue.
__global__ void k_b2prep(const float* __restrict__ zb, const float* __restrict__ w2,
                         const float* __restrict__ asrc, const float* __restrict__ adst,
                         const float* __restrict__ elw,
                         float* __restrict__ ys, float* __restrict__ yd,
                         float* __restrict__ als, float* __restrict__ ald, int n) {
    int l = threadIdx.x & 31;
    int r = blockIdx.x * (blockDim.x >> 5) + (threadIdx.x >> 5);
    if (r >= n) return;
    float zv = zb[r * HID + l];
    int gbase = threadIdx.x & 32;
    float acc = 0.f;
    #pragma unroll
    for (int k = 0; k < HID; k++) {
        float zk = __shfl(zv, gbase + k);
        acc = fmaf(zk, w2[k * HID + l], acc);
    }
    node_epilogue(acc, r, l, asrc, adst, elw, ys, yd, als, ald);
}

// One wave per node: online-softmax weighted accumulate + fused proj+BN (+pool).
template<bool POOL>
__global__ void k_gat(const int* __restrict__ offsets, const ushort_t* __restrict__ ssrc,
                      const float* __restrict__ wsum, const float* __restrict__ als,
                      const float* __restrict__ ald, const float* __restrict__ ys,
                      const float* __restrict__ yd, const float* __restrict__ elw,
                      const float* __restrict__ elb, const float* __restrict__ bvec,
                      const float* __restrict__ pw, const float* __restrict__ pb,
                      const float* __restrict__ bng, const float* __restrict__ bnb,
                      float* __restrict__ zout, float* __restrict__ pool,
                      const int* __restrict__ batch, int n) {
    int lane = threadIdx.x & 63;
    int node = blockIdx.x * (blockDim.x >> 6) + (threadIdx.x >> 6);
    if (node >= n) return;
    int beg = offsets[node], end = offsets[node + 1];
    int deg = end - beg;
    int half = lane >> 5, l = lane & 31;
    float aldi = ald[node];
    float agg;
    if (deg > 0) {
        int mid = beg + (deg >> 1);
        int e  = half ? mid : beg;
        int e1 = half ? end : mid;
        float m = -INFINITY, acc = 0.f, esum = 0.f;
        for (; e + 8 <= e1; e += 8) {
            int j0 = ssrc[e + 0], j1 = ssrc[e + 1], j2 = ssrc[e + 2], j3 = ssrc[e + 3];
            int j4 = ssrc[e + 4], j5 = ssrc[e + 5], j6 = ssrc[e + 6], j7 = ssrc[e + 7];
            float a0 = als[j0] + aldi, a1 = als[j1] + aldi, a2 = als[j2] + aldi, a3 = als[j3] + aldi;
            float a4 = als[j4] + aldi, a5 = als[j5] + aldi, a6 = als[j6] + aldi, a7 = als[j7] + aldi;
            a0 = (a0 >= 0.f) ? a0 : 0.2f * a0;  a1 = (a1 >= 0.f) ? a1 : 0.2f * a1;
            a2 = (a2 >= 0.f) ? a2 : 0.2f * a2;  a3 = (a3 >= 0.f) ? a3 : 0.2f * a3;
            a4 = (a4 >= 0.f) ? a4 : 0.2f * a4;  a5 = (a5 >= 0.f) ? a5 : 0.2f * a5;
            a6 = (a6 >= 0.f) ? a6 : 0.2f * a6;  a7 = (a7 >= 0.f) ? a7 : 0.2f * a7;
            float cmax = fmaxf(fmaxf(fmaxf(a0, a1), fmaxf(a2, a3)),
                               fmaxf(fmaxf(a4, a5), fmaxf(a6, a7)));
            if (cmax > m) { float sc = __expf(m - cmax); acc *= sc; esum *= sc; m = cmax; }
            float w0 = __expf(a0 - m), w1 = __expf(a1 - m), w2 = __expf(a2 - m), w3 = __expf(a3 - m);
            float w4 = __expf(a4 - m), w5 = __expf(a5 - m), w6 = __expf(a6 - m), w7 = __expf(a7 - m);
            acc = fmaf(w0, ys[j0 * HID + l], acc);  esum += w0;
            acc = fmaf(w1, ys[j1 * HID + l], acc);  esum += w1;
            acc = fmaf(w2, ys[j2 * HID + l], acc);  esum += w2;
            acc = fmaf(w3, ys[j3 * HID + l], acc);  esum += w3;
            acc = fmaf(w4, ys[j4 * HID + l], acc);  esum += w4;
            acc = fmaf(w5, ys[j5 * HID + l], acc);  esum += w5;
            acc = fmaf(w6, ys[j6 * HID + l], acc);  esum += w6;
            acc = fmaf(w7, ys[j7 * HID + l], acc);  esum += w7;
        }
        for (; e < e1; e++) {
            int j = ssrc[e];
            float a = als[j] + aldi;
            a = (a >= 0.f) ? a : 0.2f * a;
            if (a > m) { float sc = __expf(m - a); acc *= sc; esum *= sc; m = a; }
            float w = __expf(a - m);
            acc = fmaf(w, ys[j * HID + l], acc);
            esum += w;
        }
        // merge the two half-waves (empty half: m=-inf -> weight exp(-inf)=0)
        float mo = __shfl_xor(m, 32);
        float M  = fmaxf(m, mo);
        float c0 = __expf(m - M), c1 = __expf(mo - M);
        float se = esum * c0 + __shfl_xor(esum, 32) * c1;
        acc      = acc  * c0 + __shfl_xor(acc, 32)  * c1;
        agg = acc / se + wsum[node] * elw[64 * HID + l];
    } else {
        agg = 0.f;
    }
    agg += (float)deg * (yd[node * HID + l] + elb[l]) + bvec[l];
    // projection 32x32 via shfl broadcast, then LeakyReLU + BatchNorm(eval)
    float z = 0.f;
    #pragma unroll
    for (int k = 0; k < HID; k++) {
        float av = __shfl(agg, k);                  // agg identical on both halves
        z = fmaf(av, pw[k * HID + l], z);
    }
    z += pb[l];
    z = (z >= 0.f) ? z : 0.2f * z;
    const float inv = 0.99999500003749971875f;      // 1/sqrt(1+1e-5)
    z = fmaf(z, bng[l] * inv, bnb[l]);
    if (lane < 32) {
        if (POOL) atomicAdd(&pool[batch[node] * HID + l], z);
        else      zout[node * HID + l] = z;
    }
}

__global__ void k_head(const float* __restrict__ pool, const int* __restrict__ batch,
                       const float* __restrict__ fw, const float* __restrict__ fb,
                       float* __restrict__ out, int n, int ngraphs, int ncls) {
    __shared__ int scnt[64];
    int t = threadIdx.x;
    if (t < ngraphs) scnt[t] = 0;
    __syncthreads();
    for (int i = t; i < n; i += blockDim.x) atomicAdd(&scnt[batch[i]], 1);
    __syncthreads();
    if (t < ngraphs * ncls) {
        int g = t / ncls, c = t % ncls;
        float cc = fmaxf((float)scnt[g], 1.0f);
        float acc = 0.f;
        for (int k = 0; k < HID; k++)
            acc = fmaf(pool[g * HID + k] / cc, fw[k * ncls + c], acc);
        out[t] = acc + fb[c];
    }
}

extern "C" void kernel_launch(void* const* d_in, const int* in_sizes, int n_in,
                              void* d_out, int out_size, void* d_ws, size_t ws_size,
                              hipStream_t stream) {
    const float* x     = (const float*)d_in[0];
    const float* ea    = (const float*)d_in[1];
    const int*   eidx  = (const int*)d_in[2];
    const int*   batch = (const int*)d_in[3];
    const float* w1    = (const float*)d_in[4];
    const float* asrc1 = (const float*)d_in[5];
    const float* adst1 = (const float*)d_in[6];
    const float* b1    = (const float*)d_in[7];
    const float* elw1  = (const float*)d_in[8];
    const float* elb1  = (const float*)d_in[9];
    const float* pw1   = (const float*)d_in[10];
    const float* pb1   = (const float*)d_in[11];
    const float* bng1  = (const float*)d_in[12];
    const float* bnb1  = (const float*)d_in[13];
    const float* w2    = (const float*)d_in[14];
    const float* asrc2 = (const float*)d_in[15];
    const float* adst2 = (const float*)d_in[16];
    const float* b2    = (const float*)d_in[17];
    const float* elw2  = (const float*)d_in[18];
    const float* elb2  = (const float*)d_in[19];
    const float* pw2   = (const float*)d_in[20];
    const float* pb2   = (const float*)d_in[21];
    const float* bng2  = (const float*)d_in[22];
    const float* bnb2  = (const float*)d_in[23];
    const float* fw    = (const float*)d_in[24];
    const float* fb    = (const float*)d_in[25];

    const int E  = in_sizes[1];
    const int N  = in_sizes[3];
    const int K1 = in_sizes[4] / HID;        // 200
    const int NCLS = in_sizes[25];           // 2
    const int NG = out_size / NCLS;          // 32

    float* ws = (float*)d_ws;
    size_t off = 0;
    auto alloc = [&](size_t nelem) { size_t r = off; off += nelem; return r; };
    // zeroed region first (one memset): counts, wsum, pool
    int*      counts  = (int*)(ws + alloc(N));
    float*    wsum    = ws + alloc(N);
    float*    pool    = ws + alloc((size_t)NG * HID);
    size_t zeroN = off;
    int*      offsets = (int*)(ws + alloc(N + 1));
    int*      cursor  = (int*)(ws + alloc(N));
    ushort_t* ssrc    = (ushort_t*)(ws + alloc((E + 1) / 2));
    float*    ys      = ws + alloc((size_t)N * HID);
    float*    yd      = ws + alloc((size_t)N * HID);
    float*    zb      = ws + alloc((size_t)N * HID);
    float*    als     = ws + alloc(N);
    float*    ald     = ws + alloc(N);
    (void)ws_size; (void)n_in;

    hipMemsetAsync(ws, 0, zeroN * sizeof(float), stream);

    // ---- sort edges by dst (shared by both blocks); wsum fused into hist ----
    k_hist<<<(E + 255) / 256, 256, 0, stream>>>(eidx + E, ea, counts, wsum, E);
    k_scan<<<1, 1024, 0, stream>>>(counts, offsets, cursor, N);
    k_scatter<<<(E + 255) / 256, 256, 0, stream>>>(eidx, eidx + E, cursor, ssrc, E);

    int gb8 = (N + 7) / 8;

    // ---- block 1 ----
    k_b1prep<<<gb8, 256, K1 * HID * sizeof(float), stream>>>(
        x, w1, asrc1, adst1, elw1, ys, yd, als, ald, N, K1);
    k_gat<false><<<(N + 3) / 4, 256, 0, stream>>>(offsets, ssrc, wsum, als, ald, ys, yd,
        elw1, elb1, b1, pw1, pb1, bng1, bnb1, zb, nullptr, batch, N);

    // ---- block 2 (pool fused into gat epilogue) ----
    k_b2prep<<<gb8, 256, 0, stream>>>(zb, w2, asrc2, adst2, elw2, ys, yd, als, ald, N);
    k_gat<true><<<(N + 3) / 4, 256, 0, stream>>>(offsets, ssrc, wsum, als, ald, ys, yd,
        elw2, elb2, b2, pw2, pb2, bng2, bnb2, nullptr, pool, batch, N);

    // ---- head (computes per-graph counts itself) ----
    k_head<<<1, 256, 0, stream>>>(pool, batch, fw, fb, (float*)d_out, N, NG, NCLS);
}